// Round 16
// baseline (95.830 us; speedup 1.0000x reference)
//
#include <hip/hip_runtime.h>
#include <cmath>

// ---- problem dims ----
#define BQ 4
#define QL 1024
#define SL 4096
#define DM 256
#define NH 8
#define HD 32
#define NROWS 32768   // BQ*NH*QL
#define NSPLIT 4      // attention S-splits (4 proven: L2 dedup holds, R7/R9)
#define SEG (SL / NSPLIT)

typedef __attribute__((ext_vector_type(8))) short short8;
typedef __attribute__((ext_vector_type(4))) short short4v;
typedef __attribute__((ext_vector_type(4))) float f32x4;
typedef __attribute__((ext_vector_type(4))) unsigned int uint4v;
typedef __attribute__((ext_vector_type(2))) unsigned int uint2v;
typedef unsigned long long u64;

#define MFMA16(a, b, c) __builtin_amdgcn_mfma_f32_16x16x32_bf16((a), (b), (c), 0, 0, 0)

__device__ __forceinline__ short f2bf(float f) {
  union { float f; unsigned int u; } x; x.f = f;
  unsigned int r = x.u + 0x7FFFu + ((x.u >> 16) & 1u);  // RNE
  return (short)(r >> 16);
}
__device__ __forceinline__ unsigned int fu(float f) {
  union { float f; unsigned int u; } x; x.f = f; return x.u;
}
// 2x f32 -> packed bf16 pair in one VALU op (T12 recipe: no builtin on gfx950)
__device__ __forceinline__ unsigned int cvtpk(float lo, float hi) {
  unsigned int r;
  asm("v_cvt_pk_bf16_f32 %0, %1, %2" : "=v"(r) : "v"(lo), "v"(hi));
  return r;
}

// ---------------------------------------------------------------------------
// Fused prep: blocks 0..127 convert the 4 weight matrices f32->bf16 (512KB);
// blocks 128..1151 do mask->transposed-bits + query LayerNorm. The mask
// element-size detect is done IN-BLOCK from a 4KB sample (L2-hot; all-zero
// degenerate falls to mode4 whose bit extraction is identically zero).
// Bit layout (matches attn): bitpos = gg*16 + f*4 + r for s-local j=16f+4gg+r.
__global__ __launch_bounds__(256) void prep_kernel(const float* __restrict__ wq,
                                                   const float* __restrict__ wk,
                                                   const float* __restrict__ wv,
                                                   const float* __restrict__ wo,
                                                   const void* __restrict__ mask,
                                                   short* __restrict__ w16,
                                                   u64* __restrict__ MB,
                                                   const float* __restrict__ x,
                                                   const float* __restrict__ gw,
                                                   const float* __restrict__ bw,
                                                   short* __restrict__ xout) {
  const int bid = blockIdx.x;
  if (bid < 128) {
    // --- weight conversion ---
    const int i = bid * 256 + threadIdx.x;  // 32768 chunks of 8
    const float* src;
    short* dst;
    if (i < 8192)       { src = wq + i * 8;            dst = w16 + i * 8; }
    else if (i < 16384) { src = wk + (i - 8192) * 8;   dst = w16 + 65536 + (i - 8192) * 8; }
    else if (i < 24576) { src = wv + (i - 16384) * 8;  dst = w16 + 131072 + (i - 16384) * 8; }
    else                { src = wo + (i - 24576) * 8;  dst = w16 + 196608 + (i - 24576) * 8; }
    f32x4 a0 = *(const f32x4*)src;
    f32x4 a1 = *(const f32x4*)(src + 4);
    uint4v o = {cvtpk(a0[0], a0[1]), cvtpk(a0[2], a0[3]),
                cvtpk(a1[0], a1[1]), cvtpk(a1[2], a1[3])};
    *(uint4v*)dst = o;
    return;
  }
  const int b2 = bid - 128;
  // --- in-block detect on a 4KB sample ---
  __shared__ int fA, fB;
  if (threadIdx.x == 0) { fA = 0; fB = 0; }
  __syncthreads();
  {
    uint4v v = ((const uint4v*)mask)[threadIdx.x];
    unsigned int a = 0, bb2 = 0;
#pragma unroll
    for (int e = 0; e < 4; ++e) {
      a |= (v[e] & 0xFEFEFEFEu);   // any byte > 1  -> float-like
      bb2 |= (v[e] & 0xFFFFFF00u); // nonzero byte at %4!=0 -> bool-like
    }
    if (a) atomicOr(&fA, 1);
    if (bb2) atomicOr(&fB, 1);
  }
  __syncthreads();
  const bool mode4 = (fA || !fB);
  // --- maskbits part ---
  const int i = b2 * 256 + threadIdx.x;  // word index, 262144 total
  u64 bits = 0;
  if (mode4) {
    const uint4v* src = (const uint4v*)mask + (size_t)i * 16;
#pragma unroll
    for (int c = 0; c < 16; ++c) {
      uint4v v = src[c];
      unsigned int nib = 0;
#pragma unroll
      for (int e = 0; e < 4; ++e) nib |= (v[e] != 0u ? 1u : 0u) << e;
      bits |= (u64)nib << ((c & 3) * 16 + (c >> 2) * 4);
    }
  } else {
    const uint4v* src = (const uint4v*)mask + (size_t)i * 4;
#pragma unroll
    for (int c = 0; c < 4; ++c) {
      uint4v v = src[c];
#pragma unroll
      for (int e4 = 0; e4 < 4; ++e4) {
        const unsigned int u = v[e4];
        unsigned int nib = 0;
        nib |= (u & 0x000000FFu) ? 1u : 0u;
        nib |= (u & 0x0000FF00u) ? 2u : 0u;
        nib |= (u & 0x00FF0000u) ? 4u : 0u;
        nib |= (u & 0xFF000000u) ? 8u : 0u;
        bits |= (u64)nib << (e4 * 16 + c * 4);
      }
    }
  }
  MB[i] = bits;
  // --- layernorm part (independent; one wave per row, 4 rows/block) ---
  const int lane = threadIdx.x & 63;
  const int row = b2 * 4 + (threadIdx.x >> 6);
  const float* xr = x + (size_t)row * DM;
  f32x4 v = *(const f32x4*)(xr + lane * 4);
  float s = v[0] + v[1] + v[2] + v[3];
  float s2 = v[0]*v[0] + v[1]*v[1] + v[2]*v[2] + v[3]*v[3];
#pragma unroll
  for (int m = 1; m < 64; m <<= 1) { s += __shfl_xor(s, m); s2 += __shfl_xor(s2, m); }
  const float mu = s * (1.0f / DM);
  const float var = s2 * (1.0f / DM) - mu * mu;
  const float inv = rsqrtf(var + 1e-5f);
  f32x4 gv = *(const f32x4*)(gw + lane * 4);
  f32x4 bv = *(const f32x4*)(bw + lane * 4);
  float y0 = (v[0] - mu) * inv * gv[0] + bv[0];
  float y1 = (v[1] - mu) * inv * gv[1] + bv[1];
  float y2 = (v[2] - mu) * inv * gv[2] + bv[2];
  float y3 = (v[3] - mu) * inv * gv[3] + bv[3];
  uint2v o = {cvtpk(y0, y1), cvtpk(y2, y3)};
  *(uint2v*)(xout + (size_t)row * DM + lane * 4) = o;
}

// ---------------------------------------------------------------------------
// Fused projections, 3072 blocks, SINGLE-STAGE FULL-K (K=256 staged once,
// ONE mid-kernel barrier, then all MFMAs back-to-back):
//   [0,1024)    q-proj:  32x32-tile, A = xln bf16, out bf16 * qscale
//   [1024,2048) k-proj:  64x64-tile, A = key f32 (cvt at stage), out bf16
//   [2048,3072) v-proj:  64x64-tile, A = value f32, out bf16 transposed [b][d][s]
// LDS [64][264] (row stride 528B -> 2-way/free on b128 fragment reads, m136).
__global__ __launch_bounds__(256) void proj_kernel(const short* __restrict__ xln,
                                                   const float* __restrict__ key,
                                                   const float* __restrict__ value,
                                                   const short* __restrict__ w16,
                                                   const float* __restrict__ bq,
                                                   const float* __restrict__ bk,
                                                   const float* __restrict__ bv,
                                                   short* __restrict__ qb,
                                                   short* __restrict__ kb,
                                                   short* __restrict__ vbT,
                                                   float qscale) {
  __shared__ __align__(16) short As[64][264];
  __shared__ __align__(16) short Bs[64][264];
  const int bid = blockIdx.x;
  const int t = threadIdx.x;
  const int lane = t & 63, w = t >> 6;
  const int wm = w >> 1, wn = w & 1;
  const int g = lane >> 4, lr = lane & 15, gsh = g * 4;

  if (bid < 1024) {
    // ---------------- q-proj (32x32 tile, full-K) ----------------
    const int x = bid & 7, j = bid >> 3;          // 8 XCDs x 128
    const int m0 = (x * 16 + (j >> 3)) * 32;
    const int n0 = (j & 7) * 32;
    const int row = t >> 3, cb = (t & 7) * 32;    // 32 rows x 8 col-chunks of 32
    const int trow = m0 + row;
    short8 a4[4], b4[4];
#pragma unroll
    for (int jj = 0; jj < 4; ++jj) {
      a4[jj] = *(const short8*)(xln + (size_t)trow * DM + cb + jj * 8);
      b4[jj] = *(const short8*)(w16 + (size_t)(n0 + row) * DM + cb + jj * 8);
    }
#pragma unroll
    for (int jj = 0; jj < 4; ++jj) {
      *(short8*)&As[row][cb + jj * 8] = a4[jj];
      *(short8*)&Bs[row][cb + jj * 8] = b4[jj];
    }
    __syncthreads();
    f32x4 acc = {0.f, 0.f, 0.f, 0.f};
#pragma unroll
    for (int kk = 0; kk < 8; ++kk) {
      short8 af = *(const short8*)&As[wm * 16 + lr][kk * 32 + g * 8];
      short8 bf = *(const short8*)&Bs[wn * 16 + lr][kk * 32 + g * 8];
      acc = MFMA16(af, bf, acc);
    }
    __syncthreads();
    const int nl = wn * 16 + lr;
    const float bvv = bq[n0 + nl];
#pragma unroll
    for (int r = 0; r < 4; ++r)
      As[wm * 16 + gsh + r][nl] = f2bf((acc[r] + bvv) * qscale);
    __syncthreads();
    *(short4v*)(qb + (size_t)trow * DM + n0 + (t & 7) * 4) =
        *(const short4v*)&As[row][(t & 7) * 4];
    return;
  }

  // ---------------- k-proj / v-proj (64x64 tile, full-K) ----------------
  const bool isK = (bid < 2048);
  const int bid2 = bid - (isK ? 1024 : 2048);
  const float* Af = isK ? key : value;
  const short* W16 = w16 + (isK ? 65536 : 131072);
  const float* bias = isK ? bk : bv;
  const int x = bid2 & 7, j = bid2 >> 3;
  const int m0 = (x * 32 + (j >> 2)) * 64;     // Mt=256, 32 per XCD
  const int n0 = (j & 3) * 64;
  const int r = t >> 2, cb = (t & 3) * 64;     // 64 rows x 4 col-chunks of 64

  f32x4 av[16];
  short8 bv8[8];
#pragma unroll
  for (int jj = 0; jj < 16; ++jj)
    av[jj] = *(const f32x4*)(Af + (size_t)(m0 + r) * DM + cb + jj * 4);
#pragma unroll
  for (int jj = 0; jj < 8; ++jj)
    bv8[jj] = *(const short8*)(W16 + (size_t)(n0 + r) * DM + cb + jj * 8);
#pragma unroll
  for (int jj = 0; jj < 8; ++jj) {
    uint4v sv = {cvtpk(av[2 * jj][0], av[2 * jj][1]), cvtpk(av[2 * jj][2], av[2 * jj][3]),
                 cvtpk(av[2 * jj + 1][0], av[2 * jj + 1][1]),
                 cvtpk(av[2 * jj + 1][2], av[2 * jj + 1][3])};
    *(uint4v*)&As[r][cb + jj * 8] = sv;
    *(short8*)&Bs[r][cb + jj * 8] = bv8[jj];
  }
  __syncthreads();
  f32x4 acc[2][2] = {};
#pragma unroll
  for (int kk = 0; kk < 8; ++kk) {
    short8 af[2], bfr[2];
#pragma unroll
    for (int i = 0; i < 2; ++i) af[i] = *(const short8*)&As[wm * 32 + i * 16 + lr][kk * 32 + g * 8];
#pragma unroll
    for (int jj = 0; jj < 2; ++jj) bfr[jj] = *(const short8*)&Bs[wn * 32 + jj * 16 + lr][kk * 32 + g * 8];
#pragma unroll
    for (int i = 0; i < 2; ++i)
#pragma unroll
      for (int jj = 0; jj < 2; ++jj) acc[i][jj] = MFMA16(af[i], bfr[jj], acc[i][jj]);
  }
  __syncthreads();
  // C layout: row = g*4 + reg, col = lr [m89-verified]
  if (isK) {
#pragma unroll
    for (int i = 0; i < 2; ++i)
#pragma unroll
      for (int jj = 0; jj < 2; ++jj) {
        const int nl = wn * 32 + jj * 16 + lr;
        const float bvv = bias[n0 + nl];
#pragma unroll
        for (int rr = 0; rr < 4; ++rr)
          As[wm * 32 + i * 16 + gsh + rr][nl] = f2bf(acc[i][jj][rr] + bvv);
      }
    __syncthreads();
#pragma unroll
    for (int c = 0; c < 2; ++c) {
      const int idx = t * 2 + c, dl = idx >> 3, ch = idx & 7;
      *(short8*)(kb + (size_t)(m0 + dl) * DM + n0 + ch * 8) =
          *(const short8*)&As[dl][ch * 8];
    }
  } else {  // v-proj: transpose -> [b][d][s]
#pragma unroll
    for (int i = 0; i < 2; ++i)
#pragma unroll
      for (int jj = 0; jj < 2; ++jj) {
        const int nl = wn * 32 + jj * 16 + lr;
        const float bvv = bias[n0 + nl];
        uint2v pk2 = {cvtpk(acc[i][jj][0] + bvv, acc[i][jj][1] + bvv),
                      cvtpk(acc[i][jj][2] + bvv, acc[i][jj][3] + bvv)};
        *(uint2v*)&As[nl][wm * 32 + i * 16 + gsh] = pk2;
      }
    __syncthreads();
    const int bidx = m0 >> 12, sbase = m0 & (SL - 1);
#pragma unroll
    for (int c = 0; c < 2; ++c) {
      const int idx = t * 2 + c, dl = idx >> 3, ch = idx & 7;
      *(short8*)(vbT + ((size_t)bidx * DM + n0 + dl) * SL + sbase + ch * 8) =
          *(const short8*)&As[dl][ch * 8];
    }
  }
}

// ---------------------------------------------------------------------------
// 32x32-tile out-proj GEMM with fused split-combine (A produced in-register
// from NSPLIT attention partials). Grid 1024 = 4 blocks/CU. f32 out + bias
// + residual.
__global__ __launch_bounds__(256) void outproj_kernel(const float* __restrict__ Op,
                                                      const float* __restrict__ Lp,
                                                      const short* __restrict__ W16,
                                                      const float* __restrict__ bias,
                                                      float* __restrict__ outp,
                                                      const float* __restrict__ resid) {
  __shared__ __align__(16) short As[2][32][72];
  __shared__ __align__(16) short Bs[2][32][72];
  const int t = threadIdx.x;
  const int lane = t & 63, w = t >> 6;
  const int wm = w >> 1, wn = w & 1;
  const int g = lane >> 4, lr = lane & 15, gsh = g * 4;
  const int bid = blockIdx.x;
  const int x = bid & 7, j = bid >> 3;
  const int m0 = (x * 16 + (j >> 3)) * 32;
  const int n0 = (j & 7) * 32;
  const int row = t >> 3, cc = t & 7;
  const int trow = m0 + row;
  f32x4 acc = {0.f, 0.f, 0.f, 0.f};

  auto produceA = [&](int k) -> short8 {
    const int kcol = k * 64 + cc * 8;
    const int h = kcol >> 5, hd = kcol & 31;
    const size_t rid = ((size_t)((trow >> 10) * NH + h)) * QL + (trow & (QL - 1));
    float den = 0.0f;
    f32x4 o0 = {0.f, 0.f, 0.f, 0.f}, o1 = {0.f, 0.f, 0.f, 0.f};
#pragma unroll
    for (int i = 0; i < NSPLIT; ++i) {
      const size_t base = ((size_t)i * NROWS + rid) * 32 + hd;
      den += Lp[(size_t)i * NROWS + rid];
      const f32x4 pa = *(const f32x4*)(Op + base);
      const f32x4 pb = *(const f32x4*)(Op + base + 4);
#pragma unroll
      for (int e = 0; e < 4; ++e) { o0[e] += pa[e]; o1[e] += pb[e]; }
    }
    const float inv = __builtin_amdgcn_rcpf(den);
    union { uint4v u; short8 s; } pk;
    pk.u = uint4v{cvtpk(o0[0] * inv, o0[1] * inv), cvtpk(o0[2] * inv, o0[3] * inv),
                  cvtpk(o1[0] * inv, o1[1] * inv), cvtpk(o1[2] * inv, o1[3] * inv)};
    return pk.s;
  };
  short8 aval = produceA(0);
  short8 bval = *(const short8*)(W16 + (size_t)(n0 + row) * DM + cc * 8);

  for (int k0 = 0; k0 < 4; ++k0) {
    const int buf = k0 & 1;
    *(short8*)&As[buf][row][cc * 8] = aval;
    *(short8*)&Bs[buf][row][cc * 8] = bval;
    __syncthreads();
    if (k0 < 3) {
      aval = produceA(k0 + 1);
      bval = *(const short8*)(W16 + (size_t)(n0 + row) * DM + (k0 + 1) * 64 + cc * 8);
    }
#pragma unroll
    for (int ks = 0; ks < 2; ++ks) {
      short8 af = *(const short8*)&As[buf][wm * 16 + lr][ks * 32 + g * 8];
      short8 bf = *(const short8*)&Bs[buf][wn * 16 + lr][ks * 32 + g * 8];
      acc = MFMA16(af, bf, acc);
    }
  }
#pragma unroll
  for (int r = 0; r < 4; ++r) {
    const int rr = m0 + wm * 16 + gsh + r;
    const int col = n0 + wn * 16 + lr;
    outp[(size_t)rr * DM + col] = acc[r] + bias[col] + resid[(size_t)rr * DM + col];
  }
}

// ---------------------------------------------------------------------------
// Flash attention, swapped-QK^T, no online max (p~ = exp2(s), exact 2^m
// rescale). 32 q-rows per wave — R9/R12/R14-proven geometry: NSPLIT=4,
// grid 1024, LDS-staged (R13: zero-LDS is 2.7x worse), 2-deep prefetch,
// sign-smear masking, setprio around MFMA clusters. UNCHANGED from R15.
__global__ __launch_bounds__(256, 4) void attn_kernel(const short* __restrict__ qb,
                                                      const short* __restrict__ kb,
                                                      const short* __restrict__ vbT,
                                                      const unsigned short* __restrict__ MB,
                                                      float* __restrict__ Op,
                                                      float* __restrict__ Lp) {
  __shared__ __align__(16) short Ks[2][64][40];   // [s][hd] 80B rows
  __shared__ __align__(16) short Vs[2][32][76];   // [d][s]  152B rows

  const int n_ = blockIdx.x;
  const int x_ = n_ & 7, j_ = n_ >> 3;            // j_: 0..127
  const int grp = ((j_ >> 5) << 3) + x_;          // 0..31 = h + 8*b
  const int within = j_ & 31;
  const int q0 = (within & 7) * 128;
  const int split = within >> 3;                  // 0..3
  const int h = grp & 7, b = grp >> 3;

  const int t = threadIdx.x;
  const int l = t & 63, w = t >> 6;
  const int g = l >> 4, lr = l & 15, gsh = g * 4;
  const int qbase = q0 + w * 32;
  const int srow = t >> 2, scc = t & 3;
  const int vd = t >> 3, vsc = t & 7;

  const short* Kp = kb + ((size_t)b * SL + split * SEG + srow) * DM + h * HD + scc * 8;
  const short* Vp = vbT + ((size_t)(b * NH + h) * HD + vd) * SL + split * SEG + vsc * 8;
  const unsigned short* MBp0 =
      MB + (((size_t)(b * QL) + qbase + lr) * 64 + split * (SEG / 64)) * 4 + g;
  const unsigned short* MBp1 = MBp0 + 16 * 64 * 4;

  const short8 qf0 =
      *(const short8*)(qb + ((size_t)(b * QL) + qbase + lr) * DM + h * HD + g * 8);
  const short8 qf1 =
      *(const short8*)(qb + ((size_t)(b * QL) + qbase + 16 + lr) * DM + h * HD + g * 8);

  const short ONE = (short)0x3F80;
  const short8 ONES = {ONE, ONE, ONE, ONE, ONE, ONE, ONE, ONE};
  f32x4 Ov0[2] = {}, Ov1[2] = {};
  f32x4 Ls0 = {0.f, 0.f, 0.f, 0.f}, Ls1 = {0.f, 0.f, 0.f, 0.f};

  short8 kreg[2], vreg[2];
  unsigned int mbA[2], mbB[2];
  kreg[0] = *(const short8*)Kp;
  vreg[0] = *(const short8*)Vp;
  mbA[0] = MBp0[0]; mbB[0] = MBp1[0];
  kreg[1] = *(const short8*)(Kp + (size_t)64 * DM);
  vreg[1] = *(const short8*)(Vp + 64);
  mbA[1] = MBp0[4]; mbB[1] = MBp1[4];

#pragma unroll 2
  for (int it = 0; it < SEG / 64; ++it) {
    const int buf = it & 1;
    *(short8*)&Ks[buf][srow][scc * 8] = kreg[buf];
    {
      short4v lo = {vreg[buf][0], vreg[buf][1], vreg[buf][2], vreg[buf][3]};
      short4v hi = {vreg[buf][4], vreg[buf][5], vreg[buf][6], vreg[buf][7]};
      *(short4v*)&Vs[buf][vd][vsc * 8] = lo;
      *(short4v*)&Vs[buf][vd][vsc * 8 + 4] = hi;
    }
    const unsigned int mb0 = mbA[buf], mb1 = mbB[buf];
    __syncthreads();
    if (it < SEG / 64 - 2) {
      kreg[buf] = *(const short8*)(Kp + (size_t)(it + 2) * 64 * DM);
      vreg[buf] = *(const short8*)(Vp + (it + 2) * 64);
      mbA[buf] = MBp0[(it + 2) * 4];
      mbB[buf] = MBp1[(it + 2) * 4];
    }

    const f32x4 z = {0.f, 0.f, 0.f, 0.f};
    f32x4 sc0[4], sc1[4];
    __builtin_amdgcn_s_setprio(1);
#pragma unroll
    for (int f = 0; f < 4; ++f) {
      short8 kf = *(const short8*)&Ks[buf][f * 16 + lr][g * 8];
      sc0[f] = MFMA16(kf, qf0, z);
      sc1[f] = MFMA16(kf, qf1, z);
    }
    __builtin_amdgcn_s_setprio(0);
#pragma unroll
    for (int ks = 0; ks < 2; ++ks) {
      unsigned int pk0[2][2], pk1[2][2];
#pragma unroll
      for (int fi = 0; fi < 2; ++fi) {
        const int f = 2 * ks + fi;
        unsigned int p0[4], p1[4];
#pragma unroll
        for (int r = 0; r < 4; ++r) {
          const int sh = 31 - (f * 4 + r);
          const unsigned int m0b = (unsigned int)(((int)(mb0 << sh)) >> 31);
          const unsigned int m1b = (unsigned int)(((int)(mb1 << sh)) >> 31);
          p0[r] = fu(__builtin_amdgcn_exp2f(sc0[f][r])) & m0b;
          p1[r] = fu(__builtin_amdgcn_exp2f(sc1[f][r])) & m1b;
        }
        pk0[fi][0] = __builtin_amdgcn_perm(p0[0], p0[1], 0x03020706u);
        pk0[fi][1] = __builtin_amdgcn_perm(p0[2], p0[3], 0x03020706u);
        pk1[fi][0] = __builtin_amdgcn_perm(p1[0], p1[1], 0x03020706u);
        pk1[fi][1] = __builtin_amdgcn_perm(p1[2], p1[3], 0x03020706u);
      }
      union { unsigned int u[4]; short8 v; } pa0, pa1;
      pa0.u[0] = pk0[0][0]; pa0.u[1] = pk0[0][1]; pa0.u[2] = pk0[1][0]; pa0.u[3] = pk0[1][1];
      pa1.u[0] = pk1[0][0]; pa1.u[1] = pk1[0][1]; pa1.u[2] = pk1[1][0]; pa1.u[3] = pk1[1][1];
      __builtin_amdgcn_s_setprio(1);
      Ls0 = MFMA16(pa0.v, ONES, Ls0);
      Ls1 = MFMA16(pa1.v, ONES, Ls1);
#pragma unroll
      for (int n = 0; n < 2; ++n) {
        short4v va = *(const short4v*)&Vs[buf][n * 16 + lr][(2 * ks) * 16 + gsh];
        short4v vb2 = *(const short4v*)&Vs[buf][n * 16 + lr][(2 * ks + 1) * 16 + gsh];
        union { short4v h[2]; short8 v; } vf;
        vf.h[0] = va; vf.h[1] = vb2;
        Ov0[n] = MFMA16(pa0.v, vf.v, Ov0[n]);
        Ov1[n] = MFMA16(pa1.v, vf.v, Ov1[n]);
      }
      __builtin_amdgcn_s_setprio(0);
    }
  }
  const int ridx = (b * NH + h) * QL + qbase;
  const size_t pb = (size_t)split * NROWS + ridx;
#pragma unroll
  for (int n = 0; n < 2; ++n)
#pragma unroll
    for (int r = 0; r < 4; ++r) {
      Op[(pb + gsh + r) * 32 + n * 16 + lr] = Ov0[n][r];
      Op[(pb + 16 + gsh + r) * 32 + n * 16 + lr] = Ov1[n][r];
    }
  if (lr == 0) {
#pragma unroll
    for (int r = 0; r < 4; ++r) {
      Lp[pb + gsh + r] = Ls0[r];
      Lp[pb + 16 + gsh + r] = Ls1[r];
    }
  }
}

// ---------------------------------------------------------------------------
extern "C" void kernel_launch(void* const* d_in, const int* in_sizes, int n_in,
                              void* d_out, int out_size, void* d_ws, size_t ws_size,
                              hipStream_t stream) {
  const float* query = (const float*)d_in[0];
  const float* key   = (const float*)d_in[1];
  const float* value = (const float*)d_in[2];
  const void*  mask  = d_in[3];
  const float* wq = (const float*)d_in[4];
  const float* bq = (const float*)d_in[5];
  const float* wk = (const float*)d_in[6];
  const float* bk = (const float*)d_in[7];
  const float* wv = (const float*)d_in[8];
  const float* bv = (const float*)d_in[9];
  const float* wo = (const float*)d_in[10];
  const float* bo = (const float*)d_in[11];
  const float* lng = (const float*)d_in[12];
  const float* lnb = (const float*)d_in[13];
  float* out = (float*)d_out;

  char* ws = (char*)d_ws;
  float* Lp  = (float*)(ws + (4u << 10));               // 512 KB
  short* xln = (short*)(ws + (2u << 20));               // 2 MB
  short* qb  = (short*)(ws + (4u << 20));               // 2 MB
  short* kb  = (short*)(ws + (6u << 20));               // 8 MB
  short* vbT = (short*)(ws + (14u << 20));              // 8 MB [b][d][s]
  u64*   mbt = (u64*)(ws + (22u << 20));                // 2 MB transposed mask bits
  short* w16 = (short*)(ws + (24u << 20));              // 512 KB
  float* Op  = (float*)(ws + (25u << 20));              // 16 MB f32 partial O

  const float qscale = (float)(1.4426950408889634 / sqrt((double)HD));

  prep_kernel<<<1152, 256, 0, stream>>>(wq, wk, wv, wo, mask, w16, mbt,
                                        query, lng, lnb, xln);
  proj_kernel<<<3072, 256, 0, stream>>>(xln, key, value, w16, bq, bk, bv,
                                        qb, kb, vbT, qscale);
  attn_kernel<<<1024, 256, 0, stream>>>(qb, kb, vbT, (const unsigned short*)mbt, Op, Lp);
  outproj_kernel<<<1024, 256, 0, stream>>>(Op, Lp, w16 + 196608, bo, out, query);
}

// Round 17
// 82.869 us; speedup vs baseline: 1.1564x; 1.1564x over previous
//
#include <hip/hip_runtime.h>
#include <cmath>

// ---- problem dims ----
#define BQ 4
#define QL 1024
#define SL 4096
#define DM 256
#define NH 8
#define HD 32
#define NROWS 32768   // BQ*NH*QL
#define NSPLIT 4      // attention S-splits (4 proven: L2 dedup holds, R7/R9)
#define SEG (SL / NSPLIT)

typedef __attribute__((ext_vector_type(8))) short short8;
typedef __attribute__((ext_vector_type(4))) short short4v;
typedef __attribute__((ext_vector_type(4))) float f32x4;
typedef __attribute__((ext_vector_type(4))) unsigned int uint4v;
typedef __attribute__((ext_vector_type(2))) unsigned int uint2v;
typedef unsigned long long u64;

#define MFMA16(a, b, c) __builtin_amdgcn_mfma_f32_16x16x32_bf16((a), (b), (c), 0, 0, 0)

__device__ __forceinline__ short f2bf(float f) {
  union { float f; unsigned int u; } x; x.f = f;
  unsigned int r = x.u + 0x7FFFu + ((x.u >> 16) & 1u);  // RNE
  return (short)(r >> 16);
}
__device__ __forceinline__ unsigned int fu(float f) {
  union { float f; unsigned int u; } x; x.f = f; return x.u;
}
// 2x f32 -> packed bf16 pair in one VALU op (T12 recipe: no builtin on gfx950)
__device__ __forceinline__ unsigned int cvtpk(float lo, float hi) {
  unsigned int r;
  asm("v_cvt_pk_bf16_f32 %0, %1, %2" : "=v"(r) : "v"(lo), "v"(hi));
  return r;
}

// ---------------------------------------------------------------------------
// Fused prep: blocks 0..127 convert the 4 weight matrices f32->bf16 (512KB);
// blocks 128..1151 do mask->transposed-bits + query LayerNorm. The mask
// element-size detect is done IN-BLOCK from a 4KB sample (L2-hot; all-zero
// degenerate falls to mode4 whose bit extraction is identically zero).
// Bit layout (matches attn): bitpos = gg*16 + f*4 + r for s-local j=16f+4gg+r.
__global__ __launch_bounds__(256) void prep_kernel(const float* __restrict__ wq,
                                                   const float* __restrict__ wk,
                                                   const float* __restrict__ wv,
                                                   const float* __restrict__ wo,
                                                   const void* __restrict__ mask,
                                                   short* __restrict__ w16,
                                                   u64* __restrict__ MB,
                                                   const float* __restrict__ x,
                                                   const float* __restrict__ gw,
                                                   const float* __restrict__ bw,
                                                   short* __restrict__ xout) {
  const int bid = blockIdx.x;
  if (bid < 128) {
    const int i = bid * 256 + threadIdx.x;  // 32768 chunks of 8
    const float* src;
    short* dst;
    if (i < 8192)       { src = wq + i * 8;            dst = w16 + i * 8; }
    else if (i < 16384) { src = wk + (i - 8192) * 8;   dst = w16 + 65536 + (i - 8192) * 8; }
    else if (i < 24576) { src = wv + (i - 16384) * 8;  dst = w16 + 131072 + (i - 16384) * 8; }
    else                { src = wo + (i - 24576) * 8;  dst = w16 + 196608 + (i - 24576) * 8; }
    f32x4 a0 = *(const f32x4*)src;
    f32x4 a1 = *(const f32x4*)(src + 4);
    uint4v o = {cvtpk(a0[0], a0[1]), cvtpk(a0[2], a0[3]),
                cvtpk(a1[0], a1[1]), cvtpk(a1[2], a1[3])};
    *(uint4v*)dst = o;
    return;
  }
  const int b2 = bid - 128;
  // --- in-block detect on a 4KB sample ---
  __shared__ int fA, fB;
  if (threadIdx.x == 0) { fA = 0; fB = 0; }
  __syncthreads();
  {
    uint4v v = ((const uint4v*)mask)[threadIdx.x];
    unsigned int a = 0, bb2 = 0;
#pragma unroll
    for (int e = 0; e < 4; ++e) {
      a |= (v[e] & 0xFEFEFEFEu);   // any byte > 1  -> float-like
      bb2 |= (v[e] & 0xFFFFFF00u); // nonzero byte at %4!=0 -> bool-like
    }
    if (a) atomicOr(&fA, 1);
    if (bb2) atomicOr(&fB, 1);
  }
  __syncthreads();
  const bool mode4 = (fA || !fB);
  // --- maskbits part ---
  const int i = b2 * 256 + threadIdx.x;  // word index, 262144 total
  u64 bits = 0;
  if (mode4) {
    const uint4v* src = (const uint4v*)mask + (size_t)i * 16;
#pragma unroll
    for (int c = 0; c < 16; ++c) {
      uint4v v = src[c];
      unsigned int nib = 0;
#pragma unroll
      for (int e = 0; e < 4; ++e) nib |= (v[e] != 0u ? 1u : 0u) << e;
      bits |= (u64)nib << ((c & 3) * 16 + (c >> 2) * 4);
    }
  } else {
    const uint4v* src = (const uint4v*)mask + (size_t)i * 4;
#pragma unroll
    for (int c = 0; c < 4; ++c) {
      uint4v v = src[c];
#pragma unroll
      for (int e4 = 0; e4 < 4; ++e4) {
        const unsigned int u = v[e4];
        unsigned int nib = 0;
        nib |= (u & 0x000000FFu) ? 1u : 0u;
        nib |= (u & 0x0000FF00u) ? 2u : 0u;
        nib |= (u & 0x00FF0000u) ? 4u : 0u;
        nib |= (u & 0xFF000000u) ? 8u : 0u;
        bits |= (u64)nib << (e4 * 16 + c * 4);
      }
    }
  }
  MB[i] = bits;
  // --- layernorm part (independent; one wave per row, 4 rows/block) ---
  const int lane = threadIdx.x & 63;
  const int row = b2 * 4 + (threadIdx.x >> 6);
  const float* xr = x + (size_t)row * DM;
  f32x4 v = *(const f32x4*)(xr + lane * 4);
  float s = v[0] + v[1] + v[2] + v[3];
  float s2 = v[0]*v[0] + v[1]*v[1] + v[2]*v[2] + v[3]*v[3];
#pragma unroll
  for (int m = 1; m < 64; m <<= 1) { s += __shfl_xor(s, m); s2 += __shfl_xor(s2, m); }
  const float mu = s * (1.0f / DM);
  const float var = s2 * (1.0f / DM) - mu * mu;
  const float inv = rsqrtf(var + 1e-5f);
  f32x4 gv = *(const f32x4*)(gw + lane * 4);
  f32x4 bv = *(const f32x4*)(bw + lane * 4);
  float y0 = (v[0] - mu) * inv * gv[0] + bv[0];
  float y1 = (v[1] - mu) * inv * gv[1] + bv[1];
  float y2 = (v[2] - mu) * inv * gv[2] + bv[2];
  float y3 = (v[3] - mu) * inv * gv[3] + bv[3];
  uint2v o = {cvtpk(y0, y1), cvtpk(y2, y3)};
  *(uint2v*)(xout + (size_t)row * DM + lane * 4) = o;
}

// ---------------------------------------------------------------------------
// Fused projections, 3072 blocks — R14/R15-PROVEN double-buffered version
// (R16's full-K redesign cut occupancy to 2 blocks/CU and regressed 8us):
//   [0,1024)    q-proj:  32x32-tile, A = xln bf16, out bf16 * qscale
//   [1024,2048) k-proj:  64x64-tile, A = key f32 (cvt at stage), out bf16
//   [2048,3072) v-proj:  64x64-tile, A = value f32, out bf16 transposed [b][d][s]
// All double-buffered LDS (one barrier/k-iter), XCD-grouped decode.
__global__ __launch_bounds__(256) void proj_kernel(const short* __restrict__ xln,
                                                   const float* __restrict__ key,
                                                   const float* __restrict__ value,
                                                   const short* __restrict__ w16,
                                                   const float* __restrict__ bq,
                                                   const float* __restrict__ bk,
                                                   const float* __restrict__ bv,
                                                   short* __restrict__ qb,
                                                   short* __restrict__ kb,
                                                   short* __restrict__ vbT,
                                                   float qscale) {
  __shared__ __align__(16) short As[2][64][72];
  __shared__ __align__(16) short Bs[2][64][72];
  const int bid = blockIdx.x;
  const int t = threadIdx.x;
  const int lane = t & 63, w = t >> 6;
  const int wm = w >> 1, wn = w & 1;
  const int g = lane >> 4, lr = lane & 15, gsh = g * 4;

  if (bid < 1024) {
    // ---------------- q-proj (32x32 tile) ----------------
    const int x = bid & 7, j = bid >> 3;          // 8 XCDs x 128
    const int m0 = (x * 16 + (j >> 3)) * 32;
    const int n0 = (j & 7) * 32;
    const int row = t >> 3, cc = t & 7;
    const int trow = m0 + row;
    const short* W16 = w16;  // wq
    f32x4 acc = {0.f, 0.f, 0.f, 0.f};
    short8 aval = *(const short8*)(xln + (size_t)trow * DM + cc * 8);
    short8 bval = *(const short8*)(W16 + (size_t)(n0 + row) * DM + cc * 8);
    for (int k0 = 0; k0 < 4; ++k0) {
      const int buf = k0 & 1;
      *(short8*)&As[buf][row][cc * 8] = aval;
      *(short8*)&Bs[buf][row][cc * 8] = bval;
      __syncthreads();
      if (k0 < 3) {
        aval = *(const short8*)(xln + (size_t)trow * DM + (k0 + 1) * 64 + cc * 8);
        bval = *(const short8*)(W16 + (size_t)(n0 + row) * DM + (k0 + 1) * 64 + cc * 8);
      }
#pragma unroll
      for (int ks = 0; ks < 2; ++ks) {
        short8 af = *(const short8*)&As[buf][wm * 16 + lr][ks * 32 + g * 8];
        short8 bf = *(const short8*)&Bs[buf][wn * 16 + lr][ks * 32 + g * 8];
        acc = MFMA16(af, bf, acc);
      }
    }
    const int nl = wn * 16 + lr;
    const float bvv = bq[n0 + nl];
#pragma unroll
    for (int r = 0; r < 4; ++r)
      As[0][wm * 16 + gsh + r][nl] = f2bf((acc[r] + bvv) * qscale);
    __syncthreads();
    *(short4v*)(qb + (size_t)trow * DM + n0 + (t & 7) * 4) =
        *(const short4v*)&As[0][row][(t & 7) * 4];
    return;
  }

  // ---------------- k-proj / v-proj (64x64 tile) ----------------
  const bool isK = (bid < 2048);
  const int bid2 = bid - (isK ? 1024 : 2048);
  const float* Af = isK ? key : value;
  const short* W16 = w16 + (isK ? 65536 : 131072);
  const float* bias = isK ? bk : bv;
  const int x = bid2 & 7, j = bid2 >> 3;
  const int m0 = (x * 32 + (j >> 2)) * 64;     // Mt=256, 32 per XCD
  const int n0 = (j & 3) * 64;
  const int row = (t * 2) >> 3, cc0 = (t * 2) & 7;
  f32x4 acc[2][2] = {};

  f32x4 apf[2][2];
  short8 bn[2];
#pragma unroll
  for (int c = 0; c < 2; ++c) {
    const float* s = Af + (size_t)(m0 + row) * DM + (cc0 + c) * 8;
    apf[c][0] = *(const f32x4*)s;
    apf[c][1] = *(const f32x4*)(s + 4);
    bn[c] = *(const short8*)(W16 + (size_t)(n0 + row) * DM + (cc0 + c) * 8);
  }
  for (int k0 = 0; k0 < 4; ++k0) {
    const int buf = k0 & 1;
#pragma unroll
    for (int c = 0; c < 2; ++c) {
      uint4v sv = {cvtpk(apf[c][0][0], apf[c][0][1]), cvtpk(apf[c][0][2], apf[c][0][3]),
                   cvtpk(apf[c][1][0], apf[c][1][1]), cvtpk(apf[c][1][2], apf[c][1][3])};
      *(uint4v*)&As[buf][row][(cc0 + c) * 8] = sv;
      *(short8*)&Bs[buf][row][(cc0 + c) * 8] = bn[c];
    }
    __syncthreads();
    if (k0 < 3) {
#pragma unroll
      for (int c = 0; c < 2; ++c) {
        const float* s = Af + (size_t)(m0 + row) * DM + (k0 + 1) * 64 + (cc0 + c) * 8;
        apf[c][0] = *(const f32x4*)s;
        apf[c][1] = *(const f32x4*)(s + 4);
        bn[c] = *(const short8*)(W16 + (size_t)(n0 + row) * DM + (k0 + 1) * 64 + (cc0 + c) * 8);
      }
    }
#pragma unroll
    for (int ks = 0; ks < 2; ++ks) {
      short8 af[2], bfr[2];
#pragma unroll
      for (int i = 0; i < 2; ++i) af[i] = *(const short8*)&As[buf][wm * 32 + i * 16 + lr][ks * 32 + g * 8];
#pragma unroll
      for (int jj = 0; jj < 2; ++jj) bfr[jj] = *(const short8*)&Bs[buf][wn * 32 + jj * 16 + lr][ks * 32 + g * 8];
#pragma unroll
      for (int i = 0; i < 2; ++i)
#pragma unroll
        for (int jj = 0; jj < 2; ++jj) acc[i][jj] = MFMA16(af[i], bfr[jj], acc[i][jj]);
    }
  }
  // C layout: row = g*4 + reg, col = lr [m89-verified]
  if (isK) {
#pragma unroll
    for (int i = 0; i < 2; ++i)
#pragma unroll
      for (int jj = 0; jj < 2; ++jj) {
        const int nl = wn * 32 + jj * 16 + lr;
        const float bvv = bias[n0 + nl];
#pragma unroll
        for (int r = 0; r < 4; ++r)
          As[0][wm * 32 + i * 16 + gsh + r][nl] = f2bf(acc[i][jj][r] + bvv);
      }
    __syncthreads();
#pragma unroll
    for (int c = 0; c < 2; ++c) {
      const int idx = t * 2 + c, dl = idx >> 3, ch = idx & 7;
      *(short8*)(kb + (size_t)(m0 + dl) * DM + n0 + ch * 8) =
          *(const short8*)&As[0][dl][ch * 8];
    }
  } else {  // v-proj: transpose -> [b][d][s]
#pragma unroll
    for (int i = 0; i < 2; ++i)
#pragma unroll
      for (int jj = 0; jj < 2; ++jj) {
        const int nl = wn * 32 + jj * 16 + lr;
        const float bvv = bias[n0 + nl];
        uint2v pk2 = {cvtpk(acc[i][jj][0] + bvv, acc[i][jj][1] + bvv),
                      cvtpk(acc[i][jj][2] + bvv, acc[i][jj][3] + bvv)};
        *(uint2v*)&As[0][nl][wm * 32 + i * 16 + gsh] = pk2;
      }
    __syncthreads();
    const int bidx = m0 >> 12, sbase = m0 & (SL - 1);
#pragma unroll
    for (int c = 0; c < 2; ++c) {
      const int idx = t * 2 + c, dl = idx >> 3, ch = idx & 7;
      *(short8*)(vbT + ((size_t)bidx * DM + n0 + dl) * SL + sbase + ch * 8) =
          *(const short8*)&As[0][dl][ch * 8];
    }
  }
}

// ---------------------------------------------------------------------------
// 32x32-tile out-proj GEMM with fused split-combine (A produced in-register
// from NSPLIT attention partials). Grid 1024 = 4 blocks/CU. f32 out + bias
// + residual.
__global__ __launch_bounds__(256) void outproj_kernel(const float* __restrict__ Op,
                                                      const float* __restrict__ Lp,
                                                      const short* __restrict__ W16,
                                                      const float* __restrict__ bias,
                                                      float* __restrict__ outp,
                                                      const float* __restrict__ resid) {
  __shared__ __align__(16) short As[2][32][72];
  __shared__ __align__(16) short Bs[2][32][72];
  const int t = threadIdx.x;
  const int lane = t & 63, w = t >> 6;
  const int wm = w >> 1, wn = w & 1;
  const int g = lane >> 4, lr = lane & 15, gsh = g * 4;
  const int bid = blockIdx.x;
  const int x = bid & 7, j = bid >> 3;
  const int m0 = (x * 16 + (j >> 3)) * 32;
  const int n0 = (j & 7) * 32;
  const int row = t >> 3, cc = t & 7;
  const int trow = m0 + row;
  f32x4 acc = {0.f, 0.f, 0.f, 0.f};

  auto produceA = [&](int k) -> short8 {
    const int kcol = k * 64 + cc * 8;
    const int h = kcol >> 5, hd = kcol & 31;
    const size_t rid = ((size_t)((trow >> 10) * NH + h)) * QL + (trow & (QL - 1));
    float den = 0.0f;
    f32x4 o0 = {0.f, 0.f, 0.f, 0.f}, o1 = {0.f, 0.f, 0.f, 0.f};
#pragma unroll
    for (int i = 0; i < NSPLIT; ++i) {
      const size_t base = ((size_t)i * NROWS + rid) * 32 + hd;
      den += Lp[(size_t)i * NROWS + rid];
      const f32x4 pa = *(const f32x4*)(Op + base);
      const f32x4 pb = *(const f32x4*)(Op + base + 4);
#pragma unroll
      for (int e = 0; e < 4; ++e) { o0[e] += pa[e]; o1[e] += pb[e]; }
    }
    const float inv = __builtin_amdgcn_rcpf(den);
    union { uint4v u; short8 s; } pk;
    pk.u = uint4v{cvtpk(o0[0] * inv, o0[1] * inv), cvtpk(o0[2] * inv, o0[3] * inv),
                  cvtpk(o1[0] * inv, o1[1] * inv), cvtpk(o1[2] * inv, o1[3] * inv)};
    return pk.s;
  };
  short8 aval = produceA(0);
  short8 bval = *(const short8*)(W16 + (size_t)(n0 + row) * DM + cc * 8);

  for (int k0 = 0; k0 < 4; ++k0) {
    const int buf = k0 & 1;
    *(short8*)&As[buf][row][cc * 8] = aval;
    *(short8*)&Bs[buf][row][cc * 8] = bval;
    __syncthreads();
    if (k0 < 3) {
      aval = produceA(k0 + 1);
      bval = *(const short8*)(W16 + (size_t)(n0 + row) * DM + (k0 + 1) * 64 + cc * 8);
    }
#pragma unroll
    for (int ks = 0; ks < 2; ++ks) {
      short8 af = *(const short8*)&As[buf][wm * 16 + lr][ks * 32 + g * 8];
      short8 bf = *(const short8*)&Bs[buf][wn * 16 + lr][ks * 32 + g * 8];
      acc = MFMA16(af, bf, acc);
    }
  }
#pragma unroll
  for (int r = 0; r < 4; ++r) {
    const int rr = m0 + wm * 16 + gsh + r;
    const int col = n0 + wn * 16 + lr;
    outp[(size_t)rr * DM + col] = acc[r] + bias[col] + resid[(size_t)rr * DM + col];
  }
}

// ---------------------------------------------------------------------------
// Flash attention, swapped-QK^T, no online max (p~ = exp2(s), exact 2^m
// rescale). 32 q-rows per wave — R9/R12/R14-proven geometry: NSPLIT=4,
// grid 1024, LDS-staged (R13: zero-LDS is 2.7x worse), 2-deep prefetch,
// sign-smear masking, setprio around MFMA clusters. UNCHANGED.
__global__ __launch_bounds__(256, 4) void attn_kernel(const short* __restrict__ qb,
                                                      const short* __restrict__ kb,
                                                      const short* __restrict__ vbT,
                                                      const unsigned short* __restrict__ MB,
                                                      float* __restrict__ Op,
                                                      float* __restrict__ Lp) {
  __shared__ __align__(16) short Ks[2][64][40];   // [s][hd] 80B rows
  __shared__ __align__(16) short Vs[2][32][76];   // [d][s]  152B rows

  const int n_ = blockIdx.x;
  const int x_ = n_ & 7, j_ = n_ >> 3;            // j_: 0..127
  const int grp = ((j_ >> 5) << 3) + x_;          // 0..31 = h + 8*b
  const int within = j_ & 31;
  const int q0 = (within & 7) * 128;
  const int split = within >> 3;                  // 0..3
  const int h = grp & 7, b = grp >> 3;

  const int t = threadIdx.x;
  const int l = t & 63, w = t >> 6;
  const int g = l >> 4, lr = l & 15, gsh = g * 4;
  const int qbase = q0 + w * 32;
  const int srow = t >> 2, scc = t & 3;
  const int vd = t >> 3, vsc = t & 7;

  const short* Kp = kb + ((size_t)b * SL + split * SEG + srow) * DM + h * HD + scc * 8;
  const short* Vp = vbT + ((size_t)(b * NH + h) * HD + vd) * SL + split * SEG + vsc * 8;
  const unsigned short* MBp0 =
      MB + (((size_t)(b * QL) + qbase + lr) * 64 + split * (SEG / 64)) * 4 + g;
  const unsigned short* MBp1 = MBp0 + 16 * 64 * 4;

  const short8 qf0 =
      *(const short8*)(qb + ((size_t)(b * QL) + qbase + lr) * DM + h * HD + g * 8);
  const short8 qf1 =
      *(const short8*)(qb + ((size_t)(b * QL) + qbase + 16 + lr) * DM + h * HD + g * 8);

  const short ONE = (short)0x3F80;
  const short8 ONES = {ONE, ONE, ONE, ONE, ONE, ONE, ONE, ONE};
  f32x4 Ov0[2] = {}, Ov1[2] = {};
  f32x4 Ls0 = {0.f, 0.f, 0.f, 0.f}, Ls1 = {0.f, 0.f, 0.f, 0.f};

  short8 kreg[2], vreg[2];
  unsigned int mbA[2], mbB[2];
  kreg[0] = *(const short8*)Kp;
  vreg[0] = *(const short8*)Vp;
  mbA[0] = MBp0[0]; mbB[0] = MBp1[0];
  kreg[1] = *(const short8*)(Kp + (size_t)64 * DM);
  vreg[1] = *(const short8*)(Vp + 64);
  mbA[1] = MBp0[4]; mbB[1] = MBp1[4];

#pragma unroll 2
  for (int it = 0; it < SEG / 64; ++it) {
    const int buf = it & 1;
    *(short8*)&Ks[buf][srow][scc * 8] = kreg[buf];
    {
      short4v lo = {vreg[buf][0], vreg[buf][1], vreg[buf][2], vreg[buf][3]};
      short4v hi = {vreg[buf][4], vreg[buf][5], vreg[buf][6], vreg[buf][7]};
      *(short4v*)&Vs[buf][vd][vsc * 8] = lo;
      *(short4v*)&Vs[buf][vd][vsc * 8 + 4] = hi;
    }
    const unsigned int mb0 = mbA[buf], mb1 = mbB[buf];
    __syncthreads();
    if (it < SEG / 64 - 2) {
      kreg[buf] = *(const short8*)(Kp + (size_t)(it + 2) * 64 * DM);
      vreg[buf] = *(const short8*)(Vp + (it + 2) * 64);
      mbA[buf] = MBp0[(it + 2) * 4];
      mbB[buf] = MBp1[(it + 2) * 4];
    }

    const f32x4 z = {0.f, 0.f, 0.f, 0.f};
    f32x4 sc0[4], sc1[4];
    __builtin_amdgcn_s_setprio(1);
#pragma unroll
    for (int f = 0; f < 4; ++f) {
      short8 kf = *(const short8*)&Ks[buf][f * 16 + lr][g * 8];
      sc0[f] = MFMA16(kf, qf0, z);
      sc1[f] = MFMA16(kf, qf1, z);
    }
    __builtin_amdgcn_s_setprio(0);
#pragma unroll
    for (int ks = 0; ks < 2; ++ks) {
      unsigned int pk0[2][2], pk1[2][2];
#pragma unroll
      for (int fi = 0; fi < 2; ++fi) {
        const int f = 2 * ks + fi;
        unsigned int p0[4], p1[4];
#pragma unroll
        for (int r = 0; r < 4; ++r) {
          const int sh = 31 - (f * 4 + r);
          const unsigned int m0b = (unsigned int)(((int)(mb0 << sh)) >> 31);
          const unsigned int m1b = (unsigned int)(((int)(mb1 << sh)) >> 31);
          p0[r] = fu(__builtin_amdgcn_exp2f(sc0[f][r])) & m0b;
          p1[r] = fu(__builtin_amdgcn_exp2f(sc1[f][r])) & m1b;
        }
        pk0[fi][0] = __builtin_amdgcn_perm(p0[0], p0[1], 0x03020706u);
        pk0[fi][1] = __builtin_amdgcn_perm(p0[2], p0[3], 0x03020706u);
        pk1[fi][0] = __builtin_amdgcn_perm(p1[0], p1[1], 0x03020706u);
        pk1[fi][1] = __builtin_amdgcn_perm(p1[2], p1[3], 0x03020706u);
      }
      union { unsigned int u[4]; short8 v; } pa0, pa1;
      pa0.u[0] = pk0[0][0]; pa0.u[1] = pk0[0][1]; pa0.u[2] = pk0[1][0]; pa0.u[3] = pk0[1][1];
      pa1.u[0] = pk1[0][0]; pa1.u[1] = pk1[0][1]; pa1.u[2] = pk1[1][0]; pa1.u[3] = pk1[1][1];
      __builtin_amdgcn_s_setprio(1);
      Ls0 = MFMA16(pa0.v, ONES, Ls0);
      Ls1 = MFMA16(pa1.v, ONES, Ls1);
#pragma unroll
      for (int n = 0; n < 2; ++n) {
        short4v va = *(const short4v*)&Vs[buf][n * 16 + lr][(2 * ks) * 16 + gsh];
        short4v vb2 = *(const short4v*)&Vs[buf][n * 16 + lr][(2 * ks + 1) * 16 + gsh];
        union { short4v h[2]; short8 v; } vf;
        vf.h[0] = va; vf.h[1] = vb2;
        Ov0[n] = MFMA16(pa0.v, vf.v, Ov0[n]);
        Ov1[n] = MFMA16(pa1.v, vf.v, Ov1[n]);
      }
      __builtin_amdgcn_s_setprio(0);
    }
  }
  const int ridx = (b * NH + h) * QL + qbase;
  const size_t pb = (size_t)split * NROWS + ridx;
#pragma unroll
  for (int n = 0; n < 2; ++n)
#pragma unroll
    for (int r = 0; r < 4; ++r) {
      Op[(pb + gsh + r) * 32 + n * 16 + lr] = Ov0[n][r];
      Op[(pb + 16 + gsh + r) * 32 + n * 16 + lr] = Ov1[n][r];
    }
  if (lr == 0) {
#pragma unroll
    for (int r = 0; r < 4; ++r) {
      Lp[pb + gsh + r] = Ls0[r];
      Lp[pb + 16 + gsh + r] = Ls1[r];
    }
  }
}

// ---------------------------------------------------------------------------
extern "C" void kernel_launch(void* const* d_in, const int* in_sizes, int n_in,
                              void* d_out, int out_size, void* d_ws, size_t ws_size,
                              hipStream_t stream) {
  const float* query = (const float*)d_in[0];
  const float* key   = (const float*)d_in[1];
  const float* value = (const float*)d_in[2];
  const void*  mask  = d_in[3];
  const float* wq = (const float*)d_in[4];
  const float* bq = (const float*)d_in[5];
  const float* wk = (const float*)d_in[6];
  const float* bk = (const float*)d_in[7];
  const float* wv = (const float*)d_in[8];
  const float* bv = (const float*)d_in[9];
  const float* wo = (const float*)d_in[10];
  const float* bo = (const float*)d_in[11];
  const float* lng = (const float*)d_in[12];
  const float* lnb = (const float*)d_in[13];
  float* out = (float*)d_out;

  char* ws = (char*)d_ws;
  float* Lp  = (float*)(ws + (4u << 10));               // 512 KB
  short* xln = (short*)(ws + (2u << 20));               // 2 MB
  short* qb  = (short*)(ws + (4u << 20));               // 2 MB
  short* kb  = (short*)(ws + (6u << 20));               // 8 MB
  short* vbT = (short*)(ws + (14u << 20));              // 8 MB [b][d][s]
  u64*   mbt = (u64*)(ws + (22u << 20));                // 2 MB transposed mask bits
  short* w16 = (short*)(ws + (24u << 20));              // 512 KB
  float* Op  = (float*)(ws + (25u << 20));              // 16 MB f32 partial O

  const float qscale = (float)(1.4426950408889634 / sqrt((double)HD));

  prep_kernel<<<1152, 256, 0, stream>>>(wq, wk, wv, wo, mask, w16, mbt,
                                        query, lng, lnb, xln);
  proj_kernel<<<3072, 256, 0, stream>>>(xln, key, value, w16, bq, bk, bv,
                                        qb, kb, vbT, qscale);
  attn_kernel<<<1024, 256, 0, stream>>>(qb, kb, vbT, (const unsigned short*)mbt, Op, Lp);
  outproj_kernel<<<1024, 256, 0, stream>>>(Op, Lp, w16 + 196608, bo, out, query);
}